// Round 5
// baseline (186.618 us; speedup 1.0000x reference)
//
#include <hip/hip_runtime.h>
#include <stdint.h>

// Problem constants
#define BATCH 16384
#define INDIM 256
#define DDIM  128
#define NEXP  8
#define ROWS  64          // batch rows per block: 2 row-groups x (2 row-tiles of 16)
#define THREADS 512       // 8 waves = 2 row-groups x 4 col-groups
#define NH    48          // staging intervals: (st,eb,half) half-expert slabs
#define SLABE 16384       // bf16 elems per slab (4 kt-slabs = 32 KB)

typedef __bf16 bfv8  __attribute__((ext_vector_type(8)));   // MFMA A/B frag: 8 bf16 = 4 VGPRs
typedef float  f32x4 __attribute__((ext_vector_type(4)));   // MFMA C/D frag

typedef __attribute__((address_space(1))) const void gas_void;
typedef __attribute__((address_space(3))) void las_void;

// ---------------------------------------------------------------------------
// Prep kernel (unchanged): repack Wa/Wb/Ws and Gcat into bf16 MFMA B-fragment
// layout. W frag for flattened g = st*64+e*8+kt lives at wp + g*4096 elems;
// within a kt-slab: nt*512 + lane*8, elem j = W[i][d], i = kt*32+(lane>>4)*8+j,
// d = nt*16+(lane&15).
// ---------------------------------------------------------------------------
__global__ void prep_kernel(const float* __restrict__ Wa, const float* __restrict__ Wb,
                            const float* __restrict__ Ws, const float* __restrict__ Ga,
                            const float* __restrict__ Gb, const float* __restrict__ Gs,
                            __bf16* __restrict__ wp, __bf16* __restrict__ gp) {
    int t = blockIdx.x * 256 + threadIdx.x;
    const int NW = 3 * 8 * 8 * 8 * 64;   // 98304 W-frag slots
    if (t < NW) {
        int lane = t & 63, nt = (t >> 6) & 7, kt = (t >> 9) & 7, e = (t >> 12) & 7, st = t >> 15;
        const float* W = (st == 0) ? Wa : (st == 1) ? Wb : Ws;
        int d  = nt * 16 + (lane & 15);
        int i0 = kt * 32 + (lane >> 4) * 8;
        __bf16* o = wp + (size_t)t * 8;
#pragma unroll
        for (int j = 0; j < 8; j++)
            o[j] = (__bf16)W[(size_t)(e * 256 + i0 + j) * 128 + d];
    } else if (t < NW + 2048) {
        int t2 = t - NW;
        int lane = t2 & 63, nt = (t2 >> 6) & 3, kt = t2 >> 8;
        int g  = nt * 16 + (lane & 15);
        int k0 = kt * 32 + (lane >> 4) * 8;
        __bf16* o = gp + (size_t)t2 * 8;
#pragma unroll
        for (int j = 0; j < 8; j++) {
            int k = k0 + j;
            float v = 0.f;
            if (g < 16)      v = Ga[g * 256 + k];
            else if (g < 32) v = Gb[(g - 16) * 256 + k];
            else if (g < 56) v = Gs[(g - 32) * 256 + k];
            o[j] = (__bf16)v;
        }
    }
}

// Load A fragments (2 row-tiles x 8 k-tiles), fp32->bf16, NONTEMPORAL so the
// x streams don't evict the weight working set from L2.
__device__ __forceinline__ void load_afr(const float* __restrict__ x, int rb,
                                         int l16, int quad, bfv8 afr[2][8]) {
#pragma unroll
    for (int mt = 0; mt < 2; mt++) {
        const float* xr = x + (size_t)(rb + mt * 16 + l16) * INDIM;
#pragma unroll
        for (int kt = 0; kt < 8; kt++) {
            const f32x4* p = (const f32x4*)(xr + kt * 32 + quad * 8);
            f32x4 lo = __builtin_nontemporal_load(p);
            f32x4 hi = __builtin_nontemporal_load(p + 1);
            bfv8 a;
            a[0] = (__bf16)lo[0]; a[1] = (__bf16)lo[1]; a[2] = (__bf16)lo[2]; a[3] = (__bf16)lo[3];
            a[4] = (__bf16)hi[0]; a[5] = (__bf16)hi[1]; a[6] = (__bf16)hi[2]; a[7] = (__bf16)hi[3];
            afr[mt][kt] = a;
        }
    }
}

// Stage one 32KB half-expert slab (interval h) into double buffer (h&1).
// Per wave: 4 x global_load_lds of 1KB (LDS dest = wave-uniform base +
// lane*16B, HW rule). Global src per-lane. Slab h covers wp elems
// [h*16384, h*16384+16384) = kt-slabs 4h..4h+3.
__device__ __forceinline__ void stage_half(const __bf16* __restrict__ wp,
                                           __bf16* ring, int h, int wv, int lane) {
    const __bf16* src = wp + ((size_t)h << 14) + (wv << 11) + (lane << 3);
    __bf16* dst = ring + ((h & 1) << 14) + (wv << 11);
#pragma unroll
    for (int i = 0; i < 4; i++)
        __builtin_amdgcn_global_load_lds((gas_void*)(src + (i << 9)),
                                         (las_void*)(dst + (i << 9)), 16, 0, 0);
}

// ---------------------------------------------------------------------------
// Main fused kernel. Grid 256 blocks (1/CU) x 512 threads (8 waves).
// Block owns 64 batch rows. Wave (rg,cg): rows [rg*32, rg*32+32), output cols
// [cg*32, cg*32+32). R6: coarse-grained staging pipeline — one barrier per
// 32KB half-expert slab (16 MFMA/wave between barriers, vs 4 in R5's per-kt
// lockstep which cost 1075 cyc/step). Minimum-2-phase pattern (guide T3):
//   interval h: __syncthreads()          // drains stage(h) issued at h-1
//               issue stage(h+1)         // writes buf[(h+1)&1], WAR-safe:
//                                        //   its readers finished before this barrier
//               ds_read+16 MFMA on buf[h&1]
// No inline-asm fences: plain __syncthreads orders all LDS/VMEM ops; MFMAs
// are register-only and safe to migrate. Compiler free to pipeline the whole
// 16-MFMA interval. Weight traffic: 256 blocks x 1.5MB = 384MB, all L2/L3
// (measured FETCH 56MB = x+out only, already ideal).
// ---------------------------------------------------------------------------
__launch_bounds__(THREADS, 2)
__global__ void ple_kernel(const float* __restrict__ xa, const float* __restrict__ xb,
                           const float* __restrict__ xs,
                           const float* __restrict__ ba, const float* __restrict__ bb,
                           const float* __restrict__ bs,
                           const __bf16* __restrict__ wp, const __bf16* __restrict__ gp,
                           float* __restrict__ out) {
    __shared__ __bf16 ring[2 * SLABE];      // 64 KB double-buffered slab
    __shared__ float lgt[ROWS * 64];        // 16 KB logits [row][gate]
    __shared__ float wT[64 * ROWS];         // 16 KB softmax weights [gate][row]

    const int tid  = threadIdx.x;
    const int wv   = tid >> 6;        // wave id 0..7
    const int lane = tid & 63;
    const int rg   = wv >> 2;         // row-group 0..1
    const int cg   = wv & 3;          // col-group 0..3
    const int quad = lane >> 4;
    const int l16  = lane & 15;
    const int r0   = blockIdx.x * ROWS;
    const int rb   = r0 + rg * 32;    // this wave's row base

    // Prologue: issue stage(0) immediately; it completes under phase 1
    // (phase 1's __syncthreads drains vmcnt).
    stage_half(wp, ring, 0, wv, lane);

    bfv8 afr[2][8];                   // A frags: 2 row-tiles x 8 k-tiles (64 VGPRs)

    // ---------------- Phase 1: gate logits via MFMA ----------------
    {
        const float* x = (cg == 0) ? xa : (cg == 1) ? xb : xs;  // wave-uniform
        load_afr(x, rb, l16, quad, afr);
        f32x4 acc1[2];
#pragma unroll
        for (int mt = 0; mt < 2; mt++) { f32x4 z = {0.f, 0.f, 0.f, 0.f}; acc1[mt] = z; }
#pragma unroll
        for (int kt = 0; kt < 8; kt++) {
            bfv8 gfr = *(const bfv8*)(gp + ((size_t)(kt * 4 + cg) * 64 + lane) * 8);
#pragma unroll
            for (int mt = 0; mt < 2; mt++)
                acc1[mt] = __builtin_amdgcn_mfma_f32_16x16x32_bf16(afr[mt][kt], gfr, acc1[mt], 0, 0, 0);
        }
#pragma unroll
        for (int mt = 0; mt < 2; mt++)
#pragma unroll
            for (int r = 0; r < 4; r++)
                lgt[(rg * 32 + mt * 16 + quad * 4 + r) * 64 + cg * 16 + l16] = acc1[mt][r];
    }
    __syncthreads();

    // ---------------- softmax per row (64 rows, one wave) ----------------
    if (tid < ROWS) {
        const float* L = lgt + tid * 64;
#pragma unroll
        for (int gi = 0; gi < 3; gi++) {
            const int base = (gi == 0) ? 0 : (gi == 1 ? 16 : 32);
            const int cnt  = (gi == 2) ? 24 : 16;
            float m = -1e30f;
            for (int k = 0; k < cnt; k++) m = fmaxf(m, L[base + k]);
            float s = 0.f;
            for (int k = 0; k < cnt; k++) s += __expf(L[base + k] - m);
            float inv = 1.f / s;
            for (int k = 0; k < cnt; k++) wT[(base + k) * ROWS + tid] = __expf(L[base + k] - m) * inv;
        }
    }
    __syncthreads();

    // ---------------- Phase 2: experts + gated accumulation ----------------
    float o[3][2][2][4];
#pragma unroll
    for (int oi = 0; oi < 3; oi++)
#pragma unroll
        for (int mt = 0; mt < 2; mt++)
#pragma unroll
            for (int ntl = 0; ntl < 2; ntl++)
#pragma unroll
                for (int r = 0; r < 4; r++) o[oi][mt][ntl][r] = 0.f;

#define FOLD(oi, gbase)                                                                 \
    {                                                                                   \
        _Pragma("unroll")                                                               \
        for (int mt = 0; mt < 2; mt++) {                                                \
            f32x4 gw4 = *(const f32x4*)(wT + (gbase + eb) * ROWS + rg * 32 + mt * 16 + quad * 4); \
            _Pragma("unroll")                                                           \
            for (int ntl = 0; ntl < 2; ntl++)                                           \
                _Pragma("unroll")                                                       \
                for (int r = 0; r < 4; r++)                                             \
                    o[oi][mt][ntl][r] += gw4[r] * acc[mt][ntl][r];                      \
        }                                                                               \
    }

#pragma unroll
    for (int st = 0; st < 3; st++) {
        const float* x    = (st == 0) ? xa : (st == 1) ? xb : xs;
        const float* bias = (st == 0) ? ba : (st == 1) ? bb : bs;
        load_afr(x, rb, l16, quad, afr);

#pragma unroll 1
        for (int eb = 0; eb < NEXP; eb++) {
            float b0 = bias[eb * 128 + cg * 32 + l16];
            float b1 = bias[eb * 128 + cg * 32 + 16 + l16];

            f32x4 acc[2][2];
#pragma unroll
            for (int mt = 0; mt < 2; mt++)
#pragma unroll
                for (int ntl = 0; ntl < 2; ntl++) { f32x4 z = {0.f, 0.f, 0.f, 0.f}; acc[mt][ntl] = z; }

            // acc accumulates over both half-expert intervals (kt 0..7)
#pragma unroll
            for (int half = 0; half < 2; half++) {
                const int h = st * 16 + eb * 2 + half;   // staging interval 0..47
                __syncthreads();                         // drains stage(h); all waves' slab h in LDS
                if (h + 1 < NH)
                    stage_half(wp, ring, h + 1, wv, lane);  // into buf[(h+1)&1] — readers done

                const __bf16* buf = ring + (half << 14); // (h&1) == half
#pragma unroll
                for (int kt4 = 0; kt4 < 4; kt4++) {
                    const int kt = half * 4 + kt4;
                    const __bf16* slab = buf + (kt4 << 12) + (cg << 10);
                    bfv8 bv0 = *(const bfv8*)(slab + ((size_t)lane << 3));
                    bfv8 bv1 = *(const bfv8*)(slab + 512 + ((size_t)lane << 3));
                    acc[0][0] = __builtin_amdgcn_mfma_f32_16x16x32_bf16(afr[0][kt], bv0, acc[0][0], 0, 0, 0);
                    acc[1][0] = __builtin_amdgcn_mfma_f32_16x16x32_bf16(afr[1][kt], bv0, acc[1][0], 0, 0, 0);
                    acc[0][1] = __builtin_amdgcn_mfma_f32_16x16x32_bf16(afr[0][kt], bv1, acc[0][1], 0, 0, 0);
                    acc[1][1] = __builtin_amdgcn_mfma_f32_16x16x32_bf16(afr[1][kt], bv1, acc[1][1], 0, 0, 0);
                }
            }

            // bias (per output column)
#pragma unroll
            for (int mt = 0; mt < 2; mt++)
#pragma unroll
                for (int r = 0; r < 4; r++) { acc[mt][0][r] += b0; acc[mt][1][r] += b1; }

            // gated fold. Gate table columns: a:0-15, b:16-31, s:32-55.
            if (st == 0)      { FOLD(0, 0);  FOLD(2, 32); }
            else if (st == 1) { FOLD(1, 16); FOLD(2, 40); }
            else              { FOLD(0, 8);  FOLD(1, 24); FOLD(2, 48); }
        }
    }
#undef FOLD

    // ---------------- epilogue: store 3 outputs (nontemporal) ----------------
#pragma unroll
    for (int oi = 0; oi < 3; oi++) {
        float* ob = out + (size_t)oi * BATCH * DDIM;
#pragma unroll
        for (int mt = 0; mt < 2; mt++)
#pragma unroll
            for (int r = 0; r < 4; r++) {
                int row = rb + mt * 16 + quad * 4 + r;
#pragma unroll
                for (int ntl = 0; ntl < 2; ntl++)
                    __builtin_nontemporal_store(o[oi][mt][ntl][r],
                        &ob[(size_t)row * DDIM + cg * 32 + ntl * 16 + l16]);
            }
    }
}

extern "C" void kernel_launch(void* const* d_in, const int* in_sizes, int n_in,
                              void* d_out, int out_size, void* d_ws, size_t ws_size,
                              hipStream_t stream) {
    const float* xa = (const float*)d_in[0];
    const float* xb = (const float*)d_in[1];
    const float* xs = (const float*)d_in[2];
    const float* Wa = (const float*)d_in[3];
    const float* ba = (const float*)d_in[4];
    const float* Wb = (const float*)d_in[5];
    const float* bb = (const float*)d_in[6];
    const float* Ws = (const float*)d_in[7];
    const float* bs = (const float*)d_in[8];
    const float* Ga = (const float*)d_in[9];
    const float* Gb = (const float*)d_in[10];
    const float* Gs = (const float*)d_in[11];

    __bf16* wp = (__bf16*)d_ws;                 // 1.5 MB packed expert weights
    __bf16* gp = wp + 3 * 8 * 8 * 8 * 64 * 8;   // 32 KB packed gate matrix

    prep_kernel<<<392, 256, 0, stream>>>(Wa, Wb, Ws, Ga, Gb, Gs, wp, gp);
    ple_kernel<<<BATCH / ROWS, THREADS, 0, stream>>>(xa, xb, xs, ba, bb, bs, wp, gp, (float*)d_out);
}

// Round 7
// 180.656 us; speedup vs baseline: 1.0330x; 1.0330x over previous
//
#include <hip/hip_runtime.h>
#include <stdint.h>

// Problem constants
#define BATCH 16384
#define INDIM 256
#define DDIM  128
#define NEXP  8
#define ROWS  64          // batch rows per block: 2 row-groups x (2 row-tiles of 16)
#define THREADS 512       // 8 waves = 2 row-groups x 4 col-groups
#define NSEQ  48          // staging sequence: (st, eb0, half) half-expert slabs
#define SLABE 16384       // bf16 elems per half-expert slab (4 kt-slabs = 32 KB)

typedef __bf16 bfv8  __attribute__((ext_vector_type(8)));   // MFMA A/B frag: 8 bf16 = 4 VGPRs
typedef float  f32x4 __attribute__((ext_vector_type(4)));   // MFMA C/D frag

typedef __attribute__((address_space(1))) const void gas_void;
typedef __attribute__((address_space(3))) void las_void;

// ---------------------------------------------------------------------------
// Prep kernel R7: fully coalesced rewrite (old version: scalar 4B loads at
// 512B stride, suspected ~80-95us = the dur-ple gap). One block per kt-slab
// g = st*64+e*8+kt: f32x4-coalesced load of W[e][kt*32..+32][0..128] into
// padded LDS, gather-emit the 4096-elem bf16 fragment slab with 16B stores.
// Layout (unchanged contract): wp + g*4096 + nt*512 + lane*8 + j =
//   (bf16) W_st[e*256 + kt*32 + (lane>>4)*8 + j][nt*16 + (lane&15)]
// Blocks 192..199 pack the gate matrix (same contract as before).
// ---------------------------------------------------------------------------
__global__ void prep_kernel(const float* __restrict__ Wa, const float* __restrict__ Wb,
                            const float* __restrict__ Ws, const float* __restrict__ Ga,
                            const float* __restrict__ Gb, const float* __restrict__ Gs,
                            __bf16* __restrict__ wp, __bf16* __restrict__ gp) {
    __shared__ float ws[32 * 132];          // 32 rows x 128 cols, pad 4 to spread banks
    const int b = blockIdx.x, tid = threadIdx.x;
    if (b < 192) {
        const int st = b >> 6, e = (b >> 3) & 7, kt = b & 7;
        const float* W = (st == 0) ? Wa : (st == 1) ? Wb : Ws;
        const float* src = W + (size_t)(e * 256 + kt * 32) * 128;
#pragma unroll
        for (int k = 0; k < 4; k++) {
            int idx4 = tid + k * 256;       // f32x4 index 0..1023, coalesced
            f32x4 v = *(const f32x4*)(src + (size_t)idx4 * 4);
            int row = idx4 >> 5;            // 128 floats per row = 32 f32x4
            int col = (idx4 & 31) << 2;
            ws[row * 132 + col + 0] = v[0];
            ws[row * 132 + col + 1] = v[1];
            ws[row * 132 + col + 2] = v[2];
            ws[row * 132 + col + 3] = v[3];
        }
        __syncthreads();
        __bf16* o = wp + ((size_t)b << 12);  // g == b
#pragma unroll
        for (int h2 = 0; h2 < 2; h2++) {
            int base = tid * 2 + h2;         // frag-row 0..511: base = nt*64 + lane
            int nt = base >> 6, lane = base & 63;
            int d  = nt * 16 + (lane & 15);
            int i0 = (lane >> 4) * 8;
            bfv8 ov;
#pragma unroll
            for (int j = 0; j < 8; j++) ov[j] = (__bf16)ws[(i0 + j) * 132 + d];
            *(bfv8*)(o + (size_t)base * 8) = ov;   // consecutive threads -> consecutive 32B
        }
    } else {
        // gate packing: blocks 192..199 cover t2 = 0..2047
        int t2 = (b - 192) * 256 + tid;
        int lane = t2 & 63, nt = (t2 >> 6) & 3, kt = t2 >> 8;
        int g  = nt * 16 + (lane & 15);
        int k0 = kt * 32 + (lane >> 4) * 8;
        __bf16* o = gp + (size_t)t2 * 8;
#pragma unroll
        for (int j = 0; j < 8; j++) {
            int k = k0 + j;
            float v = 0.f;
            if (g < 16)      v = Ga[g * 256 + k];
            else if (g < 32) v = Gb[(g - 16) * 256 + k];
            else if (g < 56) v = Gs[(g - 32) * 256 + k];
            o[j] = (__bf16)v;
        }
    }
}

// Load A fragments (2 row-tiles x 8 k-tiles), fp32->bf16, NONTEMPORAL so the
// x streams don't evict the weight working set from L2.
__device__ __forceinline__ void load_afr(const float* __restrict__ x, int rb,
                                         int l16, int quad, bfv8 afr[2][8]) {
#pragma unroll
    for (int mt = 0; mt < 2; mt++) {
        const float* xr = x + (size_t)(rb + mt * 16 + l16) * INDIM;
#pragma unroll
        for (int kt = 0; kt < 8; kt++) {
            const f32x4* p = (const f32x4*)(xr + kt * 32 + quad * 8);
            f32x4 lo = __builtin_nontemporal_load(p);
            f32x4 hi = __builtin_nontemporal_load(p + 1);
            bfv8 a;
            a[0] = (__bf16)lo[0]; a[1] = (__bf16)lo[1]; a[2] = (__bf16)lo[2]; a[3] = (__bf16)lo[3];
            a[4] = (__bf16)hi[0]; a[5] = (__bf16)hi[1]; a[6] = (__bf16)hi[2]; a[7] = (__bf16)hi[3];
            afr[mt][kt] = a;
        }
    }
}

// Stage one 32KB half-expert slab (physical half-slab index hslab) into ring
// buffer `slot`. Per wave: 4 x global_load_lds of 1KB (LDS dest wave-uniform
// base + lane*16B, HW rule).
__device__ __forceinline__ void stage_slab(const __bf16* __restrict__ wp,
                                           __bf16* ring, int hslab, int slot,
                                           int wv, int lane) {
    const __bf16* src = wp + ((size_t)hslab << 14) + (wv << 11) + (lane << 3);
    __bf16* dst = ring + (slot << 14) + (wv << 11);
#pragma unroll
    for (int i = 0; i < 4; i++)
        __builtin_amdgcn_global_load_lds((gas_void*)(src + (i << 9)),
                                         (las_void*)(dst + (i << 9)), 16, 0, 0);
}

// Rotation: sequence position s in [0,48) -> physical half-slab index.
// s = st*16 + eb0*2 + half; expert actually processed = (eb0 + rot) & 7.
// Rotating the (order-independent) expert loop de-correlates the addresses
// that co-resident CUs on one XCD read concurrently (R7 theory: same-address
// L2 bank contention is the ~4.5 TB/s staging ceiling seen in R4/R5/R6).
__device__ __forceinline__ int slab_of(int s, int rot) {
    int st = s >> 4, r = s & 15;
    int eb = (((r >> 1) + rot) & 7);
    return (st << 4) | (eb << 1) | (s & 1);
}

// ---------------------------------------------------------------------------
// Main fused kernel. Grid 256 blocks (1/CU) x 512 threads (8 waves).
// Block owns 64 batch rows. Wave (rg,cg): rows [rg*32,+32), cols [cg*32,+32).
// R7 = R6 coarse pipeline (one __syncthreads per 32KB half-expert slab,
// 16 MFMA/wave payload, double-buffered global_load_lds staging) + per-block
// expert-order rotation rot=(blockIdx>>3)&7 (blockIdx%8 = XCD on MI355X, so
// >>3 staggers blocks WITHIN an XCD).
//   interval s: __syncthreads()        // drains stage(s) issued at s-1
//               issue stage(s+1)       // buf (s+1)&1, WAR-safe
//               ds_read + 16 MFMA on buf s&1
// ---------------------------------------------------------------------------
__launch_bounds__(THREADS, 2)
__global__ void ple_kernel(const float* __restrict__ xa, const float* __restrict__ xb,
                           const float* __restrict__ xs,
                           const float* __restrict__ ba, const float* __restrict__ bb,
                           const float* __restrict__ bs,
                           const __bf16* __restrict__ wp, const __bf16* __restrict__ gp,
                           float* __restrict__ out) {
    __shared__ __bf16 ring[2 * SLABE];      // 64 KB double-buffered slab
    __shared__ float lgt[ROWS * 64];        // 16 KB logits [row][gate]
    __shared__ float wT[64 * ROWS];         // 16 KB softmax weights [gate][row]

    const int tid  = threadIdx.x;
    const int wv   = tid >> 6;        // wave id 0..7
    const int lane = tid & 63;
    const int rg   = wv >> 2;         // row-group 0..1
    const int cg   = wv & 3;          // col-group 0..3
    const int quad = lane >> 4;
    const int l16  = lane & 15;
    const int r0   = blockIdx.x * ROWS;
    const int rb   = r0 + rg * 32;    // this wave's row base
    const int rot  = (blockIdx.x >> 3) & 7;

    // Prologue: issue stage(seq 0) immediately; completes under phase 1
    // (phase 1's __syncthreads drains vmcnt).
    stage_slab(wp, ring, slab_of(0, rot), 0, wv, lane);

    bfv8 afr[2][8];                   // A frags: 2 row-tiles x 8 k-tiles (64 VGPRs)

    // ---------------- Phase 1: gate logits via MFMA ----------------
    {
        const float* x = (cg == 0) ? xa : (cg == 1) ? xb : xs;  // wave-uniform
        load_afr(x, rb, l16, quad, afr);
        f32x4 acc1[2];
#pragma unroll
        for (int mt = 0; mt < 2; mt++) { f32x4 z = {0.f, 0.f, 0.f, 0.f}; acc1[mt] = z; }
#pragma unroll
        for (int kt = 0; kt < 8; kt++) {
            bfv8 gfr = *(const bfv8*)(gp + ((size_t)(kt * 4 + cg) * 64 + lane) * 8);
#pragma unroll
            for (int mt = 0; mt < 2; mt++)
                acc1[mt] = __builtin_amdgcn_mfma_f32_16x16x32_bf16(afr[mt][kt], gfr, acc1[mt], 0, 0, 0);
        }
#pragma unroll
        for (int mt = 0; mt < 2; mt++)
#pragma unroll
            for (int r = 0; r < 4; r++)
                lgt[(rg * 32 + mt * 16 + quad * 4 + r) * 64 + cg * 16 + l16] = acc1[mt][r];
    }
    __syncthreads();

    // ---------------- softmax per row (64 rows, one wave) ----------------
    if (tid < ROWS) {
        const float* L = lgt + tid * 64;
#pragma unroll
        for (int gi = 0; gi < 3; gi++) {
            const int base = (gi == 0) ? 0 : (gi == 1 ? 16 : 32);
            const int cnt  = (gi == 2) ? 24 : 16;
            float m = -1e30f;
            for (int k = 0; k < cnt; k++) m = fmaxf(m, L[base + k]);
            float s = 0.f;
            for (int k = 0; k < cnt; k++) s += __expf(L[base + k] - m);
            float inv = 1.f / s;
            for (int k = 0; k < cnt; k++) wT[(base + k) * ROWS + tid] = __expf(L[base + k] - m) * inv;
        }
    }
    __syncthreads();

    // ---------------- Phase 2: experts + gated accumulation ----------------
    float o[3][2][2][4];
#pragma unroll
    for (int oi = 0; oi < 3; oi++)
#pragma unroll
        for (int mt = 0; mt < 2; mt++)
#pragma unroll
            for (int ntl = 0; ntl < 2; ntl++)
#pragma unroll
                for (int r = 0; r < 4; r++) o[oi][mt][ntl][r] = 0.f;

#define FOLD(oi, gbase)                                                                 \
    {                                                                                   \
        _Pragma("unroll")                                                               \
        for (int mt = 0; mt < 2; mt++) {                                                \
            f32x4 gw4 = *(const f32x4*)(wT + (gbase + eb) * ROWS + rg * 32 + mt * 16 + quad * 4); \
            _Pragma("unroll")                                                           \
            for (int ntl = 0; ntl < 2; ntl++)                                           \
                _Pragma("unroll")                                                       \
                for (int r = 0; r < 4; r++)                                             \
                    o[oi][mt][ntl][r] += gw4[r] * acc[mt][ntl][r];                      \
        }                                                                               \
    }

#pragma unroll
    for (int st = 0; st < 3; st++) {
        const float* x    = (st == 0) ? xa : (st == 1) ? xb : xs;
        const float* bias = (st == 0) ? ba : (st == 1) ? bb : bs;
        load_afr(x, rb, l16, quad, afr);

#pragma unroll 1
        for (int eb0 = 0; eb0 < NEXP; eb0++) {
            const int eb = (eb0 + rot) & 7;            // actual expert this block does now
            float b0 = bias[eb * 128 + cg * 32 + l16];
            float b1 = bias[eb * 128 + cg * 32 + 16 + l16];

            f32x4 acc[2][2];
#pragma unroll
            for (int mt = 0; mt < 2; mt++)
#pragma unroll
                for (int ntl = 0; ntl < 2; ntl++) { f32x4 z = {0.f, 0.f, 0.f, 0.f}; acc[mt][ntl] = z; }

            // acc accumulates over both half-expert intervals (kt 0..7)
#pragma unroll
            for (int half = 0; half < 2; half++) {
                const int s = st * 16 + eb0 * 2 + half;  // sequence position 0..47
                __syncthreads();                         // drains stage(s)
                if (s + 1 < NSEQ)
                    stage_slab(wp, ring, slab_of(s + 1, rot), (s + 1) & 1, wv, lane);

                const __bf16* buf = ring + (half << 14); // (s&1) == half
#pragma unroll
                for (int kt4 = 0; kt4 < 4; kt4++) {
                    const int kt = half * 4 + kt4;
                    const __bf16* slab = buf + (kt4 << 12) + (cg << 10);
                    bfv8 bv0 = *(const bfv8*)(slab + ((size_t)lane << 3));
                    bfv8 bv1 = *(const bfv8*)(slab + 512 + ((size_t)lane << 3));
                    acc[0][0] = __builtin_amdgcn_mfma_f32_16x16x32_bf16(afr[0][kt], bv0, acc[0][0], 0, 0, 0);
                    acc[1][0] = __builtin_amdgcn_mfma_f32_16x16x32_bf16(afr[1][kt], bv0, acc[1][0], 0, 0, 0);
                    acc[0][1] = __builtin_amdgcn_mfma_f32_16x16x32_bf16(afr[0][kt], bv1, acc[0][1], 0, 0, 0);
                    acc[1][1] = __builtin_amdgcn_mfma_f32_16x16x32_bf16(afr[1][kt], bv1, acc[1][1], 0, 0, 0);
                }
            }

            // bias (per output column)
#pragma unroll
            for (int mt = 0; mt < 2; mt++)
#pragma unroll
                for (int r = 0; r < 4; r++) { acc[mt][0][r] += b0; acc[mt][1][r] += b1; }

            // gated fold. Gate table columns: a:0-15, b:16-31, s:32-55.
            if (st == 0)      { FOLD(0, 0);  FOLD(2, 32); }
            else if (st == 1) { FOLD(1, 16); FOLD(2, 40); }
            else              { FOLD(0, 8);  FOLD(1, 24); FOLD(2, 48); }
        }
    }
#undef FOLD

    // ---------------- epilogue: store 3 outputs (nontemporal) ----------------
#pragma unroll
    for (int oi = 0; oi < 3; oi++) {
        float* ob = out + (size_t)oi * BATCH * DDIM;
#pragma unroll
        for (int mt = 0; mt < 2; mt++)
#pragma unroll
            for (int r = 0; r < 4; r++) {
                int row = rb + mt * 16 + quad * 4 + r;
#pragma unroll
                for (int ntl = 0; ntl < 2; ntl++)
                    __builtin_nontemporal_store(o[oi][mt][ntl][r],
                        &ob[(size_t)row * DDIM + cg * 32 + ntl * 16 + l16]);
            }
    }
}

extern "C" void kernel_launch(void* const* d_in, const int* in_sizes, int n_in,
                              void* d_out, int out_size, void* d_ws, size_t ws_size,
                              hipStream_t stream) {
    const float* xa = (const float*)d_in[0];
    const float* xb = (const float*)d_in[1];
    const float* xs = (const float*)d_in[2];
    const float* Wa = (const float*)d_in[3];
    const float* ba = (const float*)d_in[4];
    const float* Wb = (const float*)d_in[5];
    const float* bb = (const float*)d_in[6];
    const float* Ws = (const float*)d_in[7];
    const float* bs = (const float*)d_in[8];
    const float* Ga = (const float*)d_in[9];
    const float* Gb = (const float*)d_in[10];
    const float* Gs = (const float*)d_in[11];

    __bf16* wp = (__bf16*)d_ws;                 // 1.5 MB packed expert weights
    __bf16* gp = wp + 3 * 8 * 8 * 8 * 64 * 8;   // 32 KB packed gate matrix

    prep_kernel<<<200, 256, 0, stream>>>(Wa, Wb, Ws, Ga, Gb, Gs, wp, gp);
    ple_kernel<<<BATCH / ROWS, THREADS, 0, stream>>>(xa, xb, xs, ba, bb, bs, wp, gp, (float*)d_out);
}